// Round 2
// baseline (234.759 us; speedup 1.0000x reference)
//
#include <hip/hip_runtime.h>

// FractionalEncoding: out[b,n,j] = emb[b,n,j] + enc(j, 1/frac[b,n])
//   j in [0,512):    enc = sin(r * 1000^(-2j/1024))
//   j in [512,1024): enc = cos(r * 1000^(-2(j-512)/1024))
// B=256, N=128, D=1024.  Memory-bound: ~268 MB traffic -> ~43 us roofline.

typedef float f32x4 __attribute__((ext_vector_type(4)));

// C = -log2(1000)/512, so freq(k) = exp2f(k*C) == 1000^(-2k/1024)
#define FREQ_C   (-1.9464422431e-02f)
// RATIO = 2^C = 1000^(-2/1024): per-element frequency ratio
#define FREQ_RATIO (0.98660290549f)

__global__ __launch_bounds__(256) void frac_enc_kernel(
    const float* __restrict__ emb,
    const float* __restrict__ frac,
    float* __restrict__ out,
    int nitems)   // nitems = B*N*128 float4-pairs
{
    int idx = blockIdx.x * blockDim.x + threadIdx.x;
    int stride = gridDim.x * blockDim.x;
    for (int i = idx; i < nitems; i += stride) {
        int row = i >> 7;            // 128 float4-pairs per row
        int j   = (i & 127) << 2;    // element offset within sin-half, 0..508

        float r = 1.0f / frac[row];  // fractions strictly positive

        const f32x4* e0 = (const f32x4*)(emb + (size_t)row * 1024 + j);
        const f32x4* e1 = (const f32x4*)(emb + (size_t)row * 1024 + 512 + j);
        f32x4 v0 = *e0;
        f32x4 v1 = *e1;

        // angle(t) = r * exp2f((j+t)*C)  — one exp2, then ratio multiplies
        float a = r * exp2f((float)j * FREQ_C);

        f32x4 o0, o1;
        #pragma unroll
        for (int t = 0; t < 4; ++t) {
            float s, c;
            __sincosf(a, &s, &c);    // fast hw sin/cos (v_sin/v_cos + reduction)
            o0[t] = v0[t] + s;
            o1[t] = v1[t] + c;
            a *= FREQ_RATIO;
        }

        f32x4* p0 = (f32x4*)(out + (size_t)row * 1024 + j);
        f32x4* p1 = (f32x4*)(out + (size_t)row * 1024 + 512 + j);
        *p0 = o0;
        *p1 = o1;
    }
}

extern "C" void kernel_launch(void* const* d_in, const int* in_sizes, int n_in,
                              void* d_out, int out_size, void* d_ws, size_t ws_size,
                              hipStream_t stream) {
    const float* emb  = (const float*)d_in[0];   // [B,N,D] f32
    const float* frac = (const float*)d_in[1];   // [B,N]   f32
    // d_in[2] = d_model (1024) — fixed shape, ignored.

    float* out = (float*)d_out;

    const int B = 256, N = 128;
    const int nitems = B * N * 128;  // each item = 2 float4 loads + 2 float4 stores

    const int block = 256;
    const int grid  = 2048;          // grid-stride; ~8 iters/thread
    frac_enc_kernel<<<grid, block, 0, stream>>>(emb, frac, out, nitems);
}

// Round 4
// 224.209 us; speedup vs baseline: 1.0471x; 1.0471x over previous
//
#include <hip/hip_runtime.h>

// FractionalEncoding: out[b,n,j] = emb[b,n,j] + enc(j, 1/frac[b,n])
//   j in [0,512):    enc = sin(r * 1000^(-2j/1024))
//   j in [512,1024): enc = cos(r * 1000^(-2(j-512)/1024))
// B=256, N=128, D=1024.  Memory-bound: 268 MB traffic -> ~43 us roofline.
//
// Structure: each thread handles TWO (sin,cos) float4-pairs at pair indices
// {tid, tid + T/2} — 4 independent 16B nontemporal loads issued up front,
// then 8 sincos, then 4 nontemporal 16B stores. No grid-stride loop.

typedef float f32x4 __attribute__((ext_vector_type(4)));

// C = -log2(1000)/512, so freq(k) = exp2f(k*C) == 1000^(-2k/1024)
#define FREQ_C     (-1.9464422431e-02f)
// 2^C = per-element frequency ratio
#define FREQ_RATIO (0.98660290549f)

__device__ __forceinline__ void do_pair(int p,
                                        const float* __restrict__ emb,
                                        const float* __restrict__ frac,
                                        float* __restrict__ out)
{
    int row = p >> 7;            // 128 float4-pairs per row
    int j   = (p & 127) << 2;    // element offset in sin-half, 0..508
    size_t base = (size_t)row * 1024 + j;

    f32x4 v0 = __builtin_nontemporal_load((const f32x4*)(emb + base));
    f32x4 v1 = __builtin_nontemporal_load((const f32x4*)(emb + base + 512));
    float r  = 1.0f / frac[row];

    float a = r * exp2f((float)j * FREQ_C);
    f32x4 o0, o1;
    #pragma unroll
    for (int t = 0; t < 4; ++t) {
        float s, c;
        __sincosf(a, &s, &c);
        o0[t] = v0[t] + s;
        o1[t] = v1[t] + c;
        a *= FREQ_RATIO;
    }

    __builtin_nontemporal_store(o0, (f32x4*)(out + base));
    __builtin_nontemporal_store(o1, (f32x4*)(out + base + 512));
}

__global__ __launch_bounds__(256) void frac_enc_kernel(
    const float* __restrict__ emb,
    const float* __restrict__ frac,
    float* __restrict__ out)
{
    const int HALF = 2097152;    // T/2 pairs; total pairs T = B*N*128 = 4194304
    int tid = blockIdx.x * blockDim.x + threadIdx.x;
    // Two independent pairs per thread; addresses computed first so all four
    // 16B loads issue before the sincos chains.
    do_pair(tid,        emb, frac, out);
    do_pair(tid + HALF, emb, frac, out);
}

extern "C" void kernel_launch(void* const* d_in, const int* in_sizes, int n_in,
                              void* d_out, int out_size, void* d_ws, size_t ws_size,
                              hipStream_t stream) {
    const float* emb  = (const float*)d_in[0];   // [B,N,D] f32
    const float* frac = (const float*)d_in[1];   // [B,N]   f32
    // d_in[2] = d_model (1024) — fixed shape, ignored.
    float* out = (float*)d_out;

    // 2,097,152 threads = 8192 blocks x 256; each thread does 2 pairs.
    frac_enc_kernel<<<8192, 256, 0, stream>>>(emb, frac, out);
}